// Round 4
// baseline (371.375 us; speedup 1.0000x reference)
//
#include <hip/hip_runtime.h>
#include <hip/hip_bf16.h>

typedef __attribute__((ext_vector_type(8))) short bf16x8;
typedef __attribute__((ext_vector_type(4))) float f32x4;

#define DIM 512
#define BM 128
#define BN 128
#define BK 32

// round-to-nearest-even f32 -> bf16
static __device__ __forceinline__ unsigned short f2bf_rne(float f) {
    unsigned int u = __float_as_uint(f);
    u += 0x7fffu + ((u >> 16) & 1u);
    return (unsigned short)(u >> 16);
}

// async global->LDS 16B copy (width must be literal 16)
static __device__ __forceinline__ void async16(const void* g, void* l) {
    __builtin_amdgcn_global_load_lds((const __attribute__((address_space(1))) unsigned int*)g,
                                     (__attribute__((address_space(3))) unsigned int*)l,
                                     16, 0, 0);
}

// One wave per row: L2-normalize row of 512 f32, emit bf16.
__global__ __launch_bounds__(256) void norm_rows_kernel(const float* __restrict__ src,
                                                        unsigned short* __restrict__ dst,
                                                        int nrows) {
    int gw   = (blockIdx.x * 256 + threadIdx.x) >> 6; // global wave id = row
    int lane = threadIdx.x & 63;
    if (gw >= nrows) return;
    const float4* row = reinterpret_cast<const float4*>(src + (size_t)gw * DIM);
    // lane handles elements [8*lane, 8*lane+7]
    float4 v0 = row[2 * lane];
    float4 v1 = row[2 * lane + 1];
    float ss = v0.x*v0.x + v0.y*v0.y + v0.z*v0.z + v0.w*v0.w
             + v1.x*v1.x + v1.y*v1.y + v1.z*v1.z + v1.w*v1.w;
    #pragma unroll
    for (int off = 32; off >= 1; off >>= 1) ss += __shfl_xor(ss, off);
    float scale = 1.0f / fmaxf(sqrtf(ss), 1e-8f);
    bf16x8 o;
    o[0] = (short)f2bf_rne(v0.x * scale);
    o[1] = (short)f2bf_rne(v0.y * scale);
    o[2] = (short)f2bf_rne(v0.z * scale);
    o[3] = (short)f2bf_rne(v0.w * scale);
    o[4] = (short)f2bf_rne(v1.x * scale);
    o[5] = (short)f2bf_rne(v1.y * scale);
    o[6] = (short)f2bf_rne(v1.z * scale);
    o[7] = (short)f2bf_rne(v1.w * scale);
    *reinterpret_cast<bf16x8*>(dst + (size_t)gw * DIM + lane * 8) = o;
}

// C[MxN] = A[MxK] * B[NxK]^T, bf16 inputs, f32 out. m97 structure:
// 128x128 tile, BK=32, 4 waves (2x2), 64x64 per wave, 16x16x32 MFMA.
__global__ __launch_bounds__(256) void cos_gemm_kernel(const unsigned short* __restrict__ A,
                                                       const unsigned short* __restrict__ Bm,
                                                       float* __restrict__ C,
                                                       int M, int N, int K) {
    __shared__ __align__(16) unsigned short As[BM * BK]; // 8 KiB
    __shared__ __align__(16) unsigned short Bs[BN * BK]; // 8 KiB

    // XCD-aware swizzle (grid divisible by 8)
    int nwg = gridDim.x;
    int bid = blockIdx.x;
    int cpx = nwg >> 3;
    int swz = (bid & 7) * cpx + (bid >> 3);
    int nbn = N / BN;
    int bm = swz / nbn;
    int bn = swz % nbn;

    int tid  = threadIdx.x;
    int lane = tid & 63;
    int wv   = tid >> 6;
    int wr   = wv >> 1;   // wave row (0..1)
    int wc   = wv & 1;    // wave col (0..1)
    int fr   = lane & 15; // fragment row/col within 16
    int kq   = lane >> 4; // k-quarter (0..3), 8 bf16 each

    // staging: tile is 8192 B; 256 threads x 16 B x 2 chunks
    int boff0 = tid * 16;         // chunk 0 byte offset in tile
    int boff1 = boff0 + 4096;     // chunk 1
    int row0 = boff0 >> 6, ce0 = (boff0 & 63) >> 1; // row, col-element
    int row1 = boff1 >> 6, ce1 = (boff1 & 63) >> 1;

    const unsigned short* aSrc0 = A  + (size_t)(bm * BM + row0) * K + ce0;
    const unsigned short* aSrc1 = A  + (size_t)(bm * BM + row1) * K + ce1;
    const unsigned short* bSrc0 = Bm + (size_t)(bn * BN + row0) * K + ce0;
    const unsigned short* bSrc1 = Bm + (size_t)(bn * BN + row1) * K + ce1;

    f32x4 acc[4][4] = {};

    const int kTiles = K / BK;
    for (int kt = 0; kt < kTiles; ++kt) {
        int ko = kt * BK;
        async16(aSrc0 + ko, (char*)As + boff0);
        async16(aSrc1 + ko, (char*)As + boff1);
        async16(bSrc0 + ko, (char*)Bs + boff0);
        async16(bSrc1 + ko, (char*)Bs + boff1);
        __syncthreads(); // includes vmcnt(0) drain of global_load_lds

        bf16x8 af[4], bfr[4];
        #pragma unroll
        for (int m = 0; m < 4; ++m)
            af[m] = *reinterpret_cast<const bf16x8*>(
                (const char*)As + (wr * 64 + m * 16 + fr) * 64 + kq * 16);
        #pragma unroll
        for (int n = 0; n < 4; ++n)
            bfr[n] = *reinterpret_cast<const bf16x8*>(
                (const char*)Bs + (wc * 64 + n * 16 + fr) * 64 + kq * 16);

        #pragma unroll
        for (int m = 0; m < 4; ++m)
            #pragma unroll
            for (int n = 0; n < 4; ++n)
                acc[m][n] = __builtin_amdgcn_mfma_f32_16x16x32_bf16(
                    af[m], bfr[n], acc[m][n], 0, 0, 0);
        __syncthreads();
    }

    // epilogue: D element j of acc[m][n] -> row m*16 + kq*4 + j, col n*16 + fr
    float* Cblk = C + (size_t)(bm * BM + wr * 64) * N + bn * BN + wc * 64;
    #pragma unroll
    for (int m = 0; m < 4; ++m)
        #pragma unroll
        for (int n = 0; n < 4; ++n)
            #pragma unroll
            for (int j = 0; j < 4; ++j)
                Cblk[(size_t)(m * 16 + kq * 4 + j) * N + n * 16 + fr] = acc[m][n][j];
}

extern "C" void kernel_launch(void* const* d_in, const int* in_sizes, int n_in,
                              void* d_out, int out_size, void* d_ws, size_t ws_size,
                              hipStream_t stream) {
    const float* x = (const float*)d_in[0];
    const float* w = (const float*)d_in[1];
    float* out = (float*)d_out;
    int B = in_sizes[0] / DIM;  // 16384
    int N = in_sizes[1] / DIM;  // 4096

    unsigned short* xn = (unsigned short*)d_ws;          // [B][512] bf16
    unsigned short* wn = xn + (size_t)B * DIM;           // [N][512] bf16

    norm_rows_kernel<<<(B + 3) / 4, 256, 0, stream>>>(x, xn, B);
    norm_rows_kernel<<<(N + 3) / 4, 256, 0, stream>>>(w, wn, N);

    int grid = (B / BM) * (N / BN); // 4096, %8==0
    cos_gemm_kernel<<<grid, 256, 0, stream>>>(xn, wn, out, B, N, DIM);
}

// Round 5
// 343.452 us; speedup vs baseline: 1.0813x; 1.0813x over previous
//
#include <hip/hip_runtime.h>
#include <hip/hip_bf16.h>

typedef __attribute__((ext_vector_type(8))) short bf16x8;
typedef __attribute__((ext_vector_type(4))) float f32x4;

#define DIM 512
#define BM 256
#define BN 256
#define BK 64
#define NKT (DIM / BK)   // 8 K-tiles

// round-to-nearest-even f32 -> bf16
static __device__ __forceinline__ unsigned short f2bf_rne(float f) {
    unsigned int u = __float_as_uint(f);
    u += 0x7fffu + ((u >> 16) & 1u);
    return (unsigned short)(u >> 16);
}

// async global->LDS 16B copy (width must be literal 16)
static __device__ __forceinline__ void async16(const void* g, void* l) {
    __builtin_amdgcn_global_load_lds((const __attribute__((address_space(1))) unsigned int*)g,
                                     (__attribute__((address_space(3))) unsigned int*)l,
                                     16, 0, 0);
}

// One wave per row: L2-normalize row of 512 f32, emit bf16.
__global__ __launch_bounds__(256) void norm_rows_kernel(const float* __restrict__ src,
                                                        unsigned short* __restrict__ dst,
                                                        int nrows) {
    int gw   = (blockIdx.x * 256 + threadIdx.x) >> 6; // global wave id = row
    int lane = threadIdx.x & 63;
    if (gw >= nrows) return;
    const float4* row = reinterpret_cast<const float4*>(src + (size_t)gw * DIM);
    float4 v0 = row[2 * lane];
    float4 v1 = row[2 * lane + 1];
    float ss = v0.x*v0.x + v0.y*v0.y + v0.z*v0.z + v0.w*v0.w
             + v1.x*v1.x + v1.y*v1.y + v1.z*v1.z + v1.w*v1.w;
    #pragma unroll
    for (int off = 32; off >= 1; off >>= 1) ss += __shfl_xor(ss, off);
    float scale = 1.0f / fmaxf(sqrtf(ss), 1e-8f);
    bf16x8 o;
    o[0] = (short)f2bf_rne(v0.x * scale);
    o[1] = (short)f2bf_rne(v0.y * scale);
    o[2] = (short)f2bf_rne(v0.z * scale);
    o[3] = (short)f2bf_rne(v0.w * scale);
    o[4] = (short)f2bf_rne(v1.x * scale);
    o[5] = (short)f2bf_rne(v1.y * scale);
    o[6] = (short)f2bf_rne(v1.z * scale);
    o[7] = (short)f2bf_rne(v1.w * scale);
    *reinterpret_cast<bf16x8*>(dst + (size_t)gw * DIM + lane * 8) = o;
}

// C[16384x4096] = A[16384x512] * B[4096x512]^T, bf16 in, f32 out.
// 256x256 tile, BK=64, 8 waves (2x4), 128x64 per wave, acc[8][4].
// Double-buffered LDS (128 KiB), prefetch-next-then-compute (T3 minimal),
// chunk-swizzled LDS layout: slot(r,c) = r*8 + (c ^ (r&7))  [16B chunks]
// staged via pre-swizzled GLOBAL source + swizzled ds_read (rule #21).
__global__ __launch_bounds__(512, 2) void cos_gemm_kernel(const unsigned short* __restrict__ A,
                                                          const unsigned short* __restrict__ Bm,
                                                          float* __restrict__ C) {
    __shared__ __align__(16) unsigned short lds[2][2][BM * BK]; // 131072 B

    const int M = 16384, N = 4096, K = 512;
    (void)M;

    // XCD-aware swizzle (grid = 1024, %8 == 0 -> bijective)
    int nwg = gridDim.x;
    int bid = blockIdx.x;
    int cpx = nwg >> 3;
    int swz = (bid & 7) * cpx + (bid >> 3);
    int nbn = N / BN; // 16
    int bm = swz / nbn;
    int bn = swz % nbn;

    int tid  = threadIdx.x;
    int lane = tid & 63;
    int wv   = tid >> 6;  // 0..7
    int wr   = wv >> 2;   // 0..1 wave-row (128 rows each)
    int wc   = wv & 3;    // 0..3 wave-col (64 cols each)
    int fr   = lane & 15; // fragment row
    int kq   = lane >> 4; // k-quarter

    // staging map: thread handles linear 16B slots s = tid + 512*i (i=0..3)
    // slot s holds global chunk c = (s&7) ^ (r&7) of row r = s>>3
    int srow[4], scol[4];
    #pragma unroll
    for (int i = 0; i < 4; ++i) {
        int s = tid + 512 * i;
        int r = s >> 3;
        int c = (s & 7) ^ (r & 7);
        srow[i] = r;
        scol[i] = c * 8; // element offset of chunk within BK
    }
    const unsigned short* Abase = A  + (size_t)(bm * BM) * K;
    const unsigned short* Bbase = Bm + (size_t)(bn * BN) * K;

    f32x4 acc[8][4] = {};

    // prologue: stage K-tile 0 into buffer 0
    #pragma unroll
    for (int i = 0; i < 4; ++i) {
        async16(Abase + (size_t)srow[i] * K + scol[i],
                (char*)&lds[0][0][0] + (tid + 512 * i) * 16);
        async16(Bbase + (size_t)srow[i] * K + scol[i],
                (char*)&lds[0][1][0] + (tid + 512 * i) * 16);
    }
    __syncthreads(); // drains vmcnt(0), all waves see tile 0

    int cur = 0;
    for (int kt = 0; kt < NKT; ++kt) {
        // issue next tile's staging BEFORE compute (loads fly under MFMA)
        if (kt + 1 < NKT) {
            int nxt = cur ^ 1;
            int ko = (kt + 1) * BK;
            #pragma unroll
            for (int i = 0; i < 4; ++i) {
                async16(Abase + (size_t)srow[i] * K + ko + scol[i],
                        (char*)&lds[nxt][0][0] + (tid + 512 * i) * 16);
                async16(Bbase + (size_t)srow[i] * K + ko + scol[i],
                        (char*)&lds[nxt][1][0] + (tid + 512 * i) * 16);
            }
        }
        // compute current tile: 2 kk-phases x 32 MFMA
        const char* Abuf = (const char*)&lds[cur][0][0];
        const char* Bbuf = (const char*)&lds[cur][1][0];
        #pragma unroll
        for (int kk = 0; kk < 2; ++kk) {
            int q = kk * 4 + kq;
            bf16x8 af[8], bfv[4];
            #pragma unroll
            for (int m = 0; m < 8; ++m) {
                int row  = wr * 128 + m * 16 + fr;
                int slot = row * 8 + (q ^ (row & 7));
                af[m] = *reinterpret_cast<const bf16x8*>(Abuf + slot * 16);
            }
            #pragma unroll
            for (int n = 0; n < 4; ++n) {
                int row  = wc * 64 + n * 16 + fr;
                int slot = row * 8 + (q ^ (row & 7));
                bfv[n] = *reinterpret_cast<const bf16x8*>(Bbuf + slot * 16);
            }
            #pragma unroll
            for (int m = 0; m < 8; ++m)
                #pragma unroll
                for (int n = 0; n < 4; ++n)
                    acc[m][n] = __builtin_amdgcn_mfma_f32_16x16x32_bf16(
                        af[m], bfv[n], acc[m][n], 0, 0, 0);
        }
        __syncthreads(); // drain next-tile loads + protect buffer reuse
        cur ^= 1;
    }

    // epilogue: acc[m][n][j] -> row m*16+kq*4+j, col n*16+fr (m89/m91 mapping)
    size_t crow0 = (size_t)(bm * BM + wr * 128);
    int    ccol0 = bn * BN + wc * 64;
    #pragma unroll
    for (int m = 0; m < 8; ++m)
        #pragma unroll
        for (int n = 0; n < 4; ++n)
            #pragma unroll
            for (int j = 0; j < 4; ++j)
                C[(crow0 + m * 16 + kq * 4 + j) * N + ccol0 + n * 16 + fr] = acc[m][n][j];
}

extern "C" void kernel_launch(void* const* d_in, const int* in_sizes, int n_in,
                              void* d_out, int out_size, void* d_ws, size_t ws_size,
                              hipStream_t stream) {
    const float* x = (const float*)d_in[0];
    const float* w = (const float*)d_in[1];
    float* out = (float*)d_out;
    int B = in_sizes[0] / DIM;  // 16384
    int N = in_sizes[1] / DIM;  // 4096

    unsigned short* xn = (unsigned short*)d_ws;          // [B][512] bf16
    unsigned short* wn = xn + (size_t)B * DIM;           // [N][512] bf16

    norm_rows_kernel<<<(B + 3) / 4, 256, 0, stream>>>(x, xn, B);
    norm_rows_kernel<<<(N + 3) / 4, 256, 0, stream>>>(w, wn, N);

    int grid = (B / BM) * (N / BN); // 64 * 16 = 1024, %8==0
    cos_gemm_kernel<<<grid, 512, 0, stream>>>(xn, wn, out);
}